// Round 16
// baseline (129.727 us; speedup 1.0000x reference)
//
#include <hip/hip_runtime.h>

#define NB 32
#define NN 2048
#define ND 128
#define NSUP 2032
#define KKEEP 1016
#define MM 1032
#define SEG 254              // NSUP / 8 segments per batch
#define RPB 12               // rows per k_newa block (86 chunks x 12 = 1032)

typedef unsigned long long u64;
typedef unsigned int u32;
typedef float f32x4 __attribute__((ext_vector_type(4)));   // clang-native vec4

// Opaque IEEE f32 RN ops — compiler cannot contract/reassociate these.
__device__ __forceinline__ float mulrn(float a, float b) {
  float r;
  asm("v_mul_f32 %0, %1, %2" : "=v"(r) : "v"(a), "v"(b));
  return r;
}
__device__ __forceinline__ float addrn(float a, float b) {
  float r;
  asm("v_add_f32 %0, %1, %2" : "=v"(r) : "v"(a), "v"(b));
  return r;
}
// Single-rounded FMA — matches x86 vfmadd exactly.
__device__ __forceinline__ float fmarn(float a, float b, float c) {
  float r;
  asm("v_fma_f32 %0, %1, %2, %3" : "=v"(r) : "v"(a), "v"(b), "v"(c));
  return r;
}

// ---------------------------------------------------------------------------
// K1: bit-exact JAX/XLA-CPU f32 score (VERIFIED round 10 — do not change).
// ---------------------------------------------------------------------------
__global__ __launch_bounds__(256) void k_score(const float* __restrict__ X,
                                               const float* __restrict__ w,
                                               const float* __restrict__ bias,
                                               u64* __restrict__ keys,
                                               float* __restrict__ score) {
#pragma clang fp contract(off)
  int row = blockIdx.x * 256 + threadIdx.x;
  if (row >= NB * NN) return;
  const float* x = X + (size_t)row * ND;

  float l[16];
  #pragma unroll
  for (int k = 0; k < 16; ++k) l[k] = 0.f;
  #pragma unroll
  for (int step = 0; step < 8; ++step) {
    const float* xp = x + step * 16;
    const float* wp = w + step * 16;
    #pragma unroll
    for (int q4 = 0; q4 < 4; ++q4) {
      const float4 xv = *reinterpret_cast<const float4*>(xp + q4 * 4);
      const float4 wv = *reinterpret_cast<const float4*>(wp + q4 * 4);
      l[q4 * 4 + 0] = addrn(mulrn(xv.x, wv.x), l[q4 * 4 + 0]);
      l[q4 * 4 + 1] = addrn(mulrn(xv.y, wv.y), l[q4 * 4 + 1]);
      l[q4 * 4 + 2] = addrn(mulrn(xv.z, wv.z), l[q4 * 4 + 2]);
      l[q4 * 4 + 3] = addrn(mulrn(xv.w, wv.w), l[q4 * 4 + 3]);
    }
  }
  #pragma unroll
  for (int k = 0; k < 8; ++k) l[k] = addrn(l[k], l[k + 8]);
  #pragma unroll
  for (int k = 0; k < 4; ++k) l[k] = addrn(l[k], l[k + 4]);
  l[0] = addrn(l[0], l[2]);
  l[1] = addrn(l[1], l[3]);
  const float dot = addrn(l[0], l[1]);

  const float z = __fdiv_rn(addrn(dot, bias[0]), 100.0f);

  const float xe = -z;
  const float z2 = mulrn(xe, xe);
  float y = fmarn(1.9875691500E-4f, xe, 1.3981999507E-3f);
  y = fmarn(y, xe, 8.3334519073E-3f);
  y = fmarn(y, xe, 4.1665795894E-2f);
  y = fmarn(y, xe, 1.6666665459E-1f);
  y = fmarn(y, xe, 5.0000001201E-1f);
  y = fmarn(y, z2, xe);
  const float e = addrn(y, 1.0f);

  const float s = __fdiv_rn(1.0f, addrn(1.0f, e));

  score[row] = s;

  const u32 sb = __float_as_uint(s);   // s>0 -> bits ascending-sortable
  const int n = row & (NN - 1);
  keys[row] = ((u64)sb << 32) | (u32)n;
}

// ---------------------------------------------------------------------------
// K2 v3: rank-by-counting selection (VERIFIED round 14): rank == output
//   position under (score_bits | idx) ascending; rank < 1016 = selected.
// ---------------------------------------------------------------------------
__global__ __launch_bounds__(256) void k_rank(const u64* __restrict__ keys,
                                              const float* __restrict__ score,
                                              int* __restrict__ idxs,
                                              float* __restrict__ vals,
                                              float* __restrict__ out_idx) {
  __shared__ u64 lk[NSUP];   // 16.3 KiB
  const int b   = blockIdx.x >> 3;
  const int seg = blockIdx.x & 7;
  const int t   = threadIdx.x;
  const size_t bNN = (size_t)b * NN;
  const int    bMM = b * MM;

  for (int i = t; i < NSUP; i += 256) lk[i] = keys[bNN + i];
  __syncthreads();

  if (t < SEG) {
    const int e  = seg * SEG + t;
    const u64 my = lk[e];
    int cnt = 0;
    #pragma unroll 4
    for (int s = 0; s < NSUP; s += 4) {
      const u64 k0 = lk[s], k1 = lk[s + 1], k2 = lk[s + 2], k3 = lk[s + 3];
      cnt += (int)(k0 < my) + (int)(k1 < my) + (int)(k2 < my) + (int)(k3 < my);
    }
    if (cnt < KKEEP) {
      idxs[bMM + cnt]    = e;
      vals[bMM + cnt]    = score[bNN + e];
      out_idx[bMM + cnt] = (float)e;
    }
  } else {
    const int q   = seg * 2 + (t - SEG);   // 0..15
    const int e   = NSUP + q;
    const int pos = KKEEP + q;
    idxs[bMM + pos]    = e;
    vals[bMM + pos]    = score[bNN + e];
    out_idx[bMM + pos] = (float)e;
  }
}

// ---------------------------------------------------------------------------
// K4 v4: software-pipelined row gather (T14 async-STAGE split).
//   Each block owns 12 consecutive output rows of ONE batch. Per row:
//   issue next row's 8 KB into regs (nontemporal) -> gather current row
//   from LDS + write (hides the read latency) -> barrier -> ds_write regs
//   into the alternate buffer -> barrier. Reads and writes overlap
//   continuously instead of phase-alternating. scols staged once per block.
// ---------------------------------------------------------------------------
__global__ __launch_bounds__(256) void k_newa(const float* __restrict__ A,
                                              const float* __restrict__ X,
                                              const int* __restrict__ idxs,
                                              const float* __restrict__ vals,
                                              float* __restrict__ out_a,
                                              float* __restrict__ out_x) {
  __shared__ float buf[2][NN];   // 16 KiB double buffer
  __shared__ int   scols[MM];    // ~4 KiB
  const int t     = threadIdx.x;
  const int b     = blockIdx.x / (MM / RPB);
  const int chunk = blockIdx.x % (MM / RPB);
  const int row0  = b * MM + chunk * RPB;
  const int* cols = idxs + b * MM;
  const float* Ab = A + (size_t)b * NN * NN;
  const float* Xb = X + (size_t)b * NN * ND;

  for (int c = t; c < MM / 4; c += 256)
    *reinterpret_cast<int4*>(&scols[c * 4]) =
        reinterpret_cast<const int4*>(cols)[c];

  // prologue: row0 -> regs -> buf0
  f32x4 r0, r1;
  {
    const f32x4* ar = reinterpret_cast<const f32x4*>(Ab + (size_t)idxs[row0] * NN);
    r0 = __builtin_nontemporal_load(ar + t);
    r1 = __builtin_nontemporal_load(ar + 256 + t);
  }
  reinterpret_cast<f32x4*>(buf[0])[t]       = r0;
  reinterpret_cast<f32x4*>(buf[0])[256 + t] = r1;
  __syncthreads();

  int cur = 0;
  for (int r = 0; r < RPB; ++r) {
    const int row = row0 + r;
    const bool more = (r + 1 < RPB);          // block-uniform
    if (more) {                                // issue next row early
      const f32x4* ar = reinterpret_cast<const f32x4*>(
          Ab + (size_t)idxs[row + 1] * NN);
      r0 = __builtin_nontemporal_load(ar + t);
      r1 = __builtin_nontemporal_load(ar + 256 + t);
    }

    // fused new_X for this row (32 lanes)
    if (t < 32) {
      const float v = vals[row];
      const float4 xv = reinterpret_cast<const float4*>(
          Xb + (size_t)idxs[row] * ND)[t];
      float4 o = make_float4(xv.x * v, xv.y * v, xv.z * v, xv.w * v);
      reinterpret_cast<float4*>(out_x + (size_t)row * ND)[t] = o;
    }

    // gather current row from LDS (long phase -> hides prefetch latency)
    const float* sr = buf[cur];
    f32x4* orow = reinterpret_cast<f32x4*>(out_a + (size_t)row * MM);
    for (int c = t; c < MM / 4; c += 256) {
      const int4 j4 = *reinterpret_cast<const int4*>(scols + c * 4);
      f32x4 o;
      o.x = sr[j4.x];
      o.y = sr[j4.y];
      o.z = sr[j4.z];
      o.w = sr[j4.w];
      __builtin_nontemporal_store(o, orow + c);
    }
    __syncthreads();                           // all reads of buf[cur^1] done
    if (more) {                                // stage prefetched row
      reinterpret_cast<f32x4*>(buf[cur ^ 1])[t]       = r0;
      reinterpret_cast<f32x4*>(buf[cur ^ 1])[256 + t] = r1;
    }
    __syncthreads();
    cur ^= 1;
  }
}

extern "C" void kernel_launch(void* const* d_in, const int* in_sizes, int n_in,
                              void* d_out, int out_size, void* d_ws, size_t ws_size,
                              hipStream_t stream) {
  const float* A    = (const float*)d_in[0];   // [32,2048,2048]
  const float* X    = (const float*)d_in[1];   // [32,2048,128]
  const float* w    = (const float*)d_in[2];   // [128]
  const float* bias = (const float*)d_in[3];   // [1]

  float* out0 = (float*)d_out;                          // new_A
  float* out1 = out0 + (size_t)NB * MM * MM;            // new_X
  float* out2 = out1 + (size_t)NB * MM * ND;            // idx (as f32)

  u64*   keys  = (u64*)d_ws;                 // [32][2048] u64
  float* score = (float*)(keys + NB * NN);   // [32][2048] f32
  int*   idxs  = (int*)(score + NB * NN);    // [32][1032] i32
  float* vals  = (float*)(idxs + NB * MM);   // [32][1032] f32

  hipLaunchKernelGGL(k_score, dim3(NB * NN / 256),    dim3(256), 0, stream, X, w, bias, keys, score);
  hipLaunchKernelGGL(k_rank,  dim3(NB * 8),           dim3(256), 0, stream, keys, score, idxs, vals, out2);
  hipLaunchKernelGGL(k_newa,  dim3(NB * (MM / RPB)),  dim3(256), 0, stream, A, X, idxs, vals, out0, out1);
}

// Round 17
// 109.949 us; speedup vs baseline: 1.1799x; 1.1799x over previous
//
#include <hip/hip_runtime.h>

#define NB 32
#define NN 2048
#define ND 128
#define NSUP 2032
#define KKEEP 1016
#define MM 1032
#define SEG 254              // NSUP / 8 segments per batch

typedef unsigned long long u64;
typedef unsigned int u32;
typedef float f32x4 __attribute__((ext_vector_type(4)));   // clang-native vec4

// Opaque IEEE f32 RN ops — compiler cannot contract/reassociate these.
__device__ __forceinline__ float mulrn(float a, float b) {
  float r;
  asm("v_mul_f32 %0, %1, %2" : "=v"(r) : "v"(a), "v"(b));
  return r;
}
__device__ __forceinline__ float addrn(float a, float b) {
  float r;
  asm("v_add_f32 %0, %1, %2" : "=v"(r) : "v"(a), "v"(b));
  return r;
}
// Single-rounded FMA — matches x86 vfmadd exactly.
__device__ __forceinline__ float fmarn(float a, float b, float c) {
  float r;
  asm("v_fma_f32 %0, %1, %2, %3" : "=v"(r) : "v"(a), "v"(b), "v"(c));
  return r;
}

// ---------------------------------------------------------------------------
// K1: bit-exact JAX/XLA-CPU f32 score (VERIFIED round 10 — do not change).
// ---------------------------------------------------------------------------
__global__ __launch_bounds__(256) void k_score(const float* __restrict__ X,
                                               const float* __restrict__ w,
                                               const float* __restrict__ bias,
                                               u64* __restrict__ keys,
                                               float* __restrict__ score) {
#pragma clang fp contract(off)
  int row = blockIdx.x * 256 + threadIdx.x;
  if (row >= NB * NN) return;
  const float* x = X + (size_t)row * ND;

  float l[16];
  #pragma unroll
  for (int k = 0; k < 16; ++k) l[k] = 0.f;
  #pragma unroll
  for (int step = 0; step < 8; ++step) {
    const float* xp = x + step * 16;
    const float* wp = w + step * 16;
    #pragma unroll
    for (int q4 = 0; q4 < 4; ++q4) {
      const float4 xv = *reinterpret_cast<const float4*>(xp + q4 * 4);
      const float4 wv = *reinterpret_cast<const float4*>(wp + q4 * 4);
      l[q4 * 4 + 0] = addrn(mulrn(xv.x, wv.x), l[q4 * 4 + 0]);
      l[q4 * 4 + 1] = addrn(mulrn(xv.y, wv.y), l[q4 * 4 + 1]);
      l[q4 * 4 + 2] = addrn(mulrn(xv.z, wv.z), l[q4 * 4 + 2]);
      l[q4 * 4 + 3] = addrn(mulrn(xv.w, wv.w), l[q4 * 4 + 3]);
    }
  }
  #pragma unroll
  for (int k = 0; k < 8; ++k) l[k] = addrn(l[k], l[k + 8]);
  #pragma unroll
  for (int k = 0; k < 4; ++k) l[k] = addrn(l[k], l[k + 4]);
  l[0] = addrn(l[0], l[2]);
  l[1] = addrn(l[1], l[3]);
  const float dot = addrn(l[0], l[1]);

  const float z = __fdiv_rn(addrn(dot, bias[0]), 100.0f);

  const float xe = -z;
  const float z2 = mulrn(xe, xe);
  float y = fmarn(1.9875691500E-4f, xe, 1.3981999507E-3f);
  y = fmarn(y, xe, 8.3334519073E-3f);
  y = fmarn(y, xe, 4.1665795894E-2f);
  y = fmarn(y, xe, 1.6666665459E-1f);
  y = fmarn(y, xe, 5.0000001201E-1f);
  y = fmarn(y, z2, xe);
  const float e = addrn(y, 1.0f);

  const float s = __fdiv_rn(1.0f, addrn(1.0f, e));

  score[row] = s;

  const u32 sb = __float_as_uint(s);   // s>0 -> bits ascending-sortable
  const int n = row & (NN - 1);
  keys[row] = ((u64)sb << 32) | (u32)n;
}

// ---------------------------------------------------------------------------
// K2 v4: rank-by-counting (VERIFIED round 14) + rank_of_src side table:
//   rsrc[b][e] = output position of source row e (-1 if dropped). Lets the
//   gather kernel iterate in SOURCE-row order (sequential A reads).
// ---------------------------------------------------------------------------
__global__ __launch_bounds__(256) void k_rank(const u64* __restrict__ keys,
                                              const float* __restrict__ score,
                                              int* __restrict__ idxs,
                                              float* __restrict__ vals,
                                              float* __restrict__ out_idx,
                                              int* __restrict__ rsrc) {
  __shared__ u64 lk[NSUP];   // 16.3 KiB
  const int b   = blockIdx.x >> 3;
  const int seg = blockIdx.x & 7;
  const int t   = threadIdx.x;
  const size_t bNN = (size_t)b * NN;
  const int    bMM = b * MM;

  for (int i = t; i < NSUP; i += 256) lk[i] = keys[bNN + i];
  __syncthreads();

  if (t < SEG) {
    const int e  = seg * SEG + t;
    const u64 my = lk[e];
    int cnt = 0;
    #pragma unroll 4
    for (int s = 0; s < NSUP; s += 4) {
      const u64 k0 = lk[s], k1 = lk[s + 1], k2 = lk[s + 2], k3 = lk[s + 3];
      cnt += (int)(k0 < my) + (int)(k1 < my) + (int)(k2 < my) + (int)(k3 < my);
    }
    if (cnt < KKEEP) {
      idxs[bMM + cnt]    = e;
      vals[bMM + cnt]    = score[bNN + e];
      out_idx[bMM + cnt] = (float)e;
      rsrc[bNN + e]      = cnt;
    } else {
      rsrc[bNN + e]      = -1;
    }
  } else {
    const int q   = seg * 2 + (t - SEG);   // 0..15
    const int e   = NSUP + q;
    const int pos = KKEEP + q;
    idxs[bMM + pos]    = e;
    vals[bMM + pos]    = score[bNN + e];
    out_idx[bMM + pos] = (float)e;
    rsrc[bNN + e]      = pos;
  }
}

// ---------------------------------------------------------------------------
// K4 v5: SOURCE-ORDER gather. One block per (b, e): consecutive blocks read
//   consecutive A rows (ascending addresses, ~50% density -> DRAM row-buffer
//   friendly, concurrent read window ~27 MB instead of random over 537 MB).
//   Unselected rows exit immediately. Randomness moves to the write side
//   (full 4 KB rows, L2-buffered, latency-tolerant). Fused new_X.
// ---------------------------------------------------------------------------
__global__ __launch_bounds__(128) void k_newa(const float* __restrict__ A,
                                              const float* __restrict__ X,
                                              const int* __restrict__ rsrc,
                                              const int* __restrict__ idxs,
                                              const float* __restrict__ score,
                                              float* __restrict__ out_a,
                                              float* __restrict__ out_x) {
  __shared__ float srow[NN];     // 8 KiB
  __shared__ int   scols[MM];    // ~4 KiB
  const int t = threadIdx.x;
  const int b = blockIdx.x >> 11;           // / NN
  const int e = blockIdx.x & (NN - 1);
  const int r = rsrc[blockIdx.x];           // block-uniform
  if (r < 0) return;                        // dropped row: exit before barrier

  const int* cols = idxs + b * MM;
  for (int c = t; c < MM / 4; c += 128)
    *reinterpret_cast<int4*>(&scols[c * 4]) =
        reinterpret_cast<const int4*>(cols)[c];

  const float* arow = A + ((size_t)b * NN + e) * NN;
  #pragma unroll
  for (int i = 0; i < 4; ++i) {             // 2048 floats = 512 f32x4
    const int off = (t + i * 128) * 4;
    *reinterpret_cast<f32x4*>(&srow[off]) =
        __builtin_nontemporal_load(reinterpret_cast<const f32x4*>(arow + off));
  }

  const int orow_i = b * MM + r;
  if (t < 32) {                             // fused new_X
    const float v = score[(size_t)b * NN + e];   // == vals[r], bit-exact
    const float4 xv = reinterpret_cast<const float4*>(
        X + ((size_t)b * NN + e) * ND)[t];
    float4 o = make_float4(xv.x * v, xv.y * v, xv.z * v, xv.w * v);
    reinterpret_cast<float4*>(out_x + (size_t)orow_i * ND)[t] = o;
  }
  __syncthreads();

  f32x4* orow = reinterpret_cast<f32x4*>(out_a + (size_t)orow_i * MM);
  for (int c = t; c < MM / 4; c += 128) {
    const int4 j4 = *reinterpret_cast<const int4*>(scols + c * 4);
    f32x4 o;
    o.x = srow[j4.x];
    o.y = srow[j4.y];
    o.z = srow[j4.z];
    o.w = srow[j4.w];
    __builtin_nontemporal_store(o, orow + c);
  }
}

extern "C" void kernel_launch(void* const* d_in, const int* in_sizes, int n_in,
                              void* d_out, int out_size, void* d_ws, size_t ws_size,
                              hipStream_t stream) {
  const float* A    = (const float*)d_in[0];   // [32,2048,2048]
  const float* X    = (const float*)d_in[1];   // [32,2048,128]
  const float* w    = (const float*)d_in[2];   // [128]
  const float* bias = (const float*)d_in[3];   // [1]

  float* out0 = (float*)d_out;                          // new_A
  float* out1 = out0 + (size_t)NB * MM * MM;            // new_X
  float* out2 = out1 + (size_t)NB * MM * ND;            // idx (as f32)

  u64*   keys  = (u64*)d_ws;                 // [32][2048] u64
  float* score = (float*)(keys + NB * NN);   // [32][2048] f32
  int*   idxs  = (int*)(score + NB * NN);    // [32][1032] i32
  float* vals  = (float*)(idxs + NB * MM);   // [32][1032] f32
  int*   rsrc  = (int*)(vals + NB * MM);     // [32][2048] i32

  hipLaunchKernelGGL(k_score, dim3(NB * NN / 256), dim3(256), 0, stream, X, w, bias, keys, score);
  hipLaunchKernelGGL(k_rank,  dim3(NB * 8),        dim3(256), 0, stream, keys, score, idxs, vals, out2, rsrc);
  hipLaunchKernelGGL(k_newa,  dim3(NB * NN),       dim3(128), 0, stream, A, X, rsrc, idxs, score, out0, out1);
}